// Round 7
// baseline (203.539 us; speedup 1.0000x reference)
//
#include <hip/hip_runtime.h>
#include <hip/hip_bf16.h>
#include <hip/hip_cooperative_groups.h>
#include <cstdint>

// ExemplarAttention: logits[b,c] = gamma * log( sum_{n: label[n]=c} exp(-beta * d[b,n]) + eps )
// d[b,n] = x2w[b] + e2w[n] - 2 * sum_k (x[b,k]*w[k]) * E[n,k]
//
// Round 7: single cooperative kernel (256 blocks x 512 thr, 1 block/CU co-resident).
//  Phase A: per-block softmax(w) (redundant, kills serial prep_w); each block converts
//           the 64 E-rows its OWN tile consumes (XCD-local L2 production) + 4 X-rows.
//  grid.sync()
//  Phase B: round-5 validated 256x256/BK=64 dbuf MFMA loop + one-hot class reduce,
//           coalesced partial stores (no atomics).
//  grid.sync()
//  Phase C: in-kernel partial reduction + gamma*log -> out.
// Eliminates 3 kernel launches + gaps (~10 us of serial latency).

typedef __attribute__((ext_vector_type(4))) float f32x4;
typedef __attribute__((ext_vector_type(8))) __bf16 bf16x8;
typedef __attribute__((ext_vector_type(4))) _Float16 half4;
typedef __attribute__((ext_vector_type(4))) unsigned int u32x4;

#define DDIM 512
#define NC 10
#define NCP 16
#define NECH 64    // exemplar chunks (16384/256)
#define EPSF 1e-9f

typedef const __attribute__((address_space(1))) void* gas_ptr;
typedef __attribute__((address_space(3))) void* las_ptr;

__device__ inline void async16(const void* g, void* l) {
  __builtin_amdgcn_global_load_lds((gas_ptr)g, (las_ptr)l, 16, 0, 0);
}

__device__ inline unsigned short f2bf(float f) {
  unsigned int u = __float_as_uint(f);
  u += 0x7FFFu + ((u >> 16) & 1u);   // round-to-nearest-even
  return (unsigned short)(u >> 16);
}

__device__ inline float wave_sum(float v) {
  #pragma unroll
  for (int o = 32; o > 0; o >>= 1) v += __shfl_xor(v, o, 64);
  return v;
}

__device__ inline float softplus(float x) {
  return (x > 20.0f) ? x : log1pf(__expf(x));
}

__global__ __launch_bounds__(512, 2) void fused_all(
    const float* __restrict__ x, const float* __restrict__ ex,
    const int* __restrict__ labels, const float* __restrict__ wu,
    const float* __restrict__ gu, const float* __restrict__ bu,
    unsigned short* __restrict__ xbf, unsigned short* __restrict__ ebf,
    float* __restrict__ x2w, float* __restrict__ e2w,
    float* __restrict__ part, float* __restrict__ out) {
  cooperative_groups::grid_group grid = cooperative_groups::this_grid();

  // 2 buffers x (E 32KB | X 32KB) = 128KB; within a buffer X at +16384 shorts.
  __shared__ __attribute__((aligned(16))) unsigned short smem[2 * 2 * 16384];
  __shared__ int lab[256];
  const int tid = threadIdx.x, lane = tid & 63, wid = tid >> 6;

  // XCD-aware bijective swizzle: XCD x gets E-tiles [x*8, x*8+8) x 4 b-tiles.
  // All 4 blocks sharing an E-tile (bb=0..3) land on the SAME XCD.
  const int orig = blockIdx.x;              // 0..255
  const int xcd = orig & 7;
  const int local = orig >> 3;              // 0..31
  const int be = xcd * 8 + (local >> 2);    // exemplar tile 0..63
  const int bb = local & 3;                 // batch tile 0..3

  // ================= phase A: softmax(w) + bf16 conversion + row sums ==========
  {
    float* wlds = (float*)smem;            // 512 f32
    float* sm = wlds + 512;                // 16 f32
    float v = wu[tid];
    float m = v;
    #pragma unroll
    for (int o = 32; o > 0; o >>= 1) m = fmaxf(m, __shfl_xor(m, o, 64));
    if (lane == 0) sm[wid] = m;
    __syncthreads();
    float mm = sm[0];
    #pragma unroll
    for (int i = 1; i < 8; ++i) mm = fmaxf(mm, sm[i]);
    float e = __expf(v - mm);
    float s = wave_sum(e);
    if (lane == 0) sm[8 + wid] = s;
    __syncthreads();
    float ss = 0.f;
    #pragma unroll
    for (int i = 0; i < 8; ++i) ss += sm[8 + i];
    wlds[tid] = e / ss + EPSF;
    __syncthreads();

    const float4 wa = *(const float4*)&wlds[lane * 8];
    const float4 wb = *(const float4*)&wlds[lane * 8 + 4];

    // E rows: exactly the 64 rows this block's tile consumes (XCD-local L2).
    #pragma unroll
    for (int st = 0; st < 8; ++st) {
      const int row = be * 256 + bb * 64 + st * 8 + wid;
      const float* p = ex + (size_t)row * DDIM + lane * 8;
      float4 va = *(const float4*)(p);
      float4 vb = *(const float4*)(p + 4);
      float s2 = va.x * va.x * wa.x + va.y * va.y * wa.y + va.z * va.z * wa.z + va.w * va.w * wa.w
               + vb.x * vb.x * wb.x + vb.y * vb.y * wb.y + vb.z * vb.z * wb.z + vb.w * vb.w * wb.w;
      u32x4 pk;
      pk[0] = (unsigned)f2bf(va.x) | ((unsigned)f2bf(va.y) << 16);
      pk[1] = (unsigned)f2bf(va.z) | ((unsigned)f2bf(va.w) << 16);
      pk[2] = (unsigned)f2bf(vb.x) | ((unsigned)f2bf(vb.y) << 16);
      pk[3] = (unsigned)f2bf(vb.z) | ((unsigned)f2bf(vb.w) << 16);
      *(u32x4*)(ebf + (size_t)row * DDIM + lane * 8) = pk;
      s2 = wave_sum(s2);
      if (lane == 0) e2w[row] = s2;
    }
    // X rows: 4 per block (x*w in bf16 + weighted square sum).
    if (wid < 4) {
      const int row = orig * 4 + wid;
      const float* p = x + (size_t)row * DDIM + lane * 8;
      float4 va = *(const float4*)(p);
      float4 vb = *(const float4*)(p + 4);
      float s2 = va.x * va.x * wa.x + va.y * va.y * wa.y + va.z * va.z * wa.z + va.w * va.w * wa.w
               + vb.x * vb.x * wb.x + vb.y * vb.y * wb.y + vb.z * vb.z * wb.z + vb.w * vb.w * wb.w;
      u32x4 pk;
      pk[0] = (unsigned)f2bf(va.x * wa.x) | ((unsigned)f2bf(va.y * wa.y) << 16);
      pk[1] = (unsigned)f2bf(va.z * wa.z) | ((unsigned)f2bf(va.w * wa.w) << 16);
      pk[2] = (unsigned)f2bf(vb.x * wb.x) | ((unsigned)f2bf(vb.y * wb.y) << 16);
      pk[3] = (unsigned)f2bf(vb.z * wb.z) | ((unsigned)f2bf(vb.w * wb.w) << 16);
      *(u32x4*)(xbf + (size_t)row * DDIM + lane * 8) = pk;
      s2 = wave_sum(s2);
      if (lane == 0) x2w[row] = s2;
    }
  }
  __threadfence();
  grid.sync();

  // ================= phase B: GEMM + exp + one-hot class partial reduce ========
  if (tid < 256) lab[tid] = labels[be * 256 + tid];

  // staging: i = c*512 + tid in [0,2048): row = i>>3 (256 rows), ch = i&7.
  // LDS linear (global_load_lds constraint); SOURCE pre-swizzled so LDS (row,ch)
  // holds global (row, ch^(row&7)).
  const unsigned short* srcE[4];
  const unsigned short* srcX[4];
  int loff[4];
  #pragma unroll
  for (int c = 0; c < 4; ++c) {
    int i = c * 512 + tid;
    int row = i >> 3, ch = i & 7;
    int sch = ch ^ (row & 7);
    srcE[c] = ebf + (size_t)(be * 256 + row) * DDIM + sch * 8;
    srcX[c] = xbf + (size_t)(bb * 256 + row) * DDIM + sch * 8;
    loff[c] = i * 8;
  }

  const int WE = (wid >> 2) * 128;   // exemplar base (0 or 128)
  const int WB = (wid & 3) * 64;     // batch base (0,64,128,192)

  // fragment read byte-offsets within operand block, swizzle-matched
  int eoff[2][8], xoff[2][4];
  #pragma unroll
  for (int ks = 0; ks < 2; ++ks) {
    int ch = ks * 4 + (lane >> 4);
    #pragma unroll
    for (int f = 0; f < 8; ++f) {
      int erow = WE + f * 16 + (lane & 15);
      eoff[ks][f] = erow * 128 + ((ch ^ (erow & 7)) * 16);
    }
    #pragma unroll
    for (int f = 0; f < 4; ++f) {
      int xrow = WB + f * 16 + (lane & 15);
      xoff[ks][f] = xrow * 128 + ((ch ^ (xrow & 7)) * 16);
    }
  }

  // prologue: stage K-tile 0 into buffer 0
  #pragma unroll
  for (int c = 0; c < 4; ++c) {
    async16(srcE[c], &smem[loff[c]]);
    async16(srcX[c], &smem[16384 + loff[c]]);
    srcE[c] += 64; srcX[c] += 64;
  }
  __syncthreads();   // drains vmcnt -> buffer 0 ready

  f32x4 acc[8][4] = {};
  int cur = 0;
  for (int kt = 0; kt < 8; ++kt) {
    if (kt < 7) {   // issue next tile into the other buffer; lands under compute
      const int nb = (cur ^ 1) * 32768;
      #pragma unroll
      for (int c = 0; c < 4; ++c) {
        async16(srcE[c], &smem[nb + loff[c]]);
        async16(srcX[c], &smem[nb + 16384 + loff[c]]);
        srcE[c] += 64; srcX[c] += 64;
      }
    }
    const char* base = (const char*)&smem[cur * 32768];
    #pragma unroll
    for (int ks = 0; ks < 2; ++ks) {
      bf16x8 ef[8], xf[4];
      #pragma unroll
      for (int f = 0; f < 8; ++f) ef[f] = *(const bf16x8*)(base + eoff[ks][f]);
      #pragma unroll
      for (int f = 0; f < 4; ++f) xf[f] = *(const bf16x8*)(base + 32768 + xoff[ks][f]);
      #pragma unroll
      for (int fe = 0; fe < 8; ++fe)
        #pragma unroll
        for (int fb = 0; fb < 4; ++fb)
          acc[fe][fb] = __builtin_amdgcn_mfma_f32_16x16x32_bf16(ef[fe], xf[fb], acc[fe][fb], 0, 0, 0);
    }
    __syncthreads();   // all reads of cur done + next-tile loads landed
    cur ^= 1;
  }

  // epilogue: sim = exp(-beta*(x2w + e2w - 2*cross)); class-reduce via one-hot MFMA.
  const float beta = softplus(bu[0]) + EPSF;
  const int rb = (lane >> 4) * 4;   // row base within 16x16 fragment
  const int col = lane & 15;        // batch col in acc frags; class in cs frags
  float e2v[8][4];
  #pragma unroll
  for (int fe = 0; fe < 8; ++fe)
    #pragma unroll
    for (int r = 0; r < 4; ++r)
      e2v[fe][r] = e2w[be * 256 + WE + fe * 16 + rb + r];
  half4 oh[8];
  #pragma unroll
  for (int fe = 0; fe < 8; ++fe)
    #pragma unroll
    for (int i = 0; i < 4; ++i)
      oh[fe][i] = (lab[WE + fe * 16 + rb + i] == col) ? (_Float16)1.0f : (_Float16)0.0f;

  f32x4 csv[4];
  #pragma unroll
  for (int fb = 0; fb < 4; ++fb) {
    const float xv = x2w[bb * 256 + WB + fb * 16 + col];
    f32x4 cs = {0.f, 0.f, 0.f, 0.f};
    #pragma unroll
    for (int fe = 0; fe < 8; ++fe) {
      half4 sa;
      #pragma unroll
      for (int r = 0; r < 4; ++r)
        sa[r] = (_Float16)__expf(-beta * (xv + e2v[fe][r] - 2.0f * acc[fe][fb][r]));
      cs = __builtin_amdgcn_mfma_f32_16x16x16f16(sa, oh[fe], cs, 0, 0, 0);
    }
    csv[fb] = cs;   // cs[r]: class-sum for batch row (WB+fb*16+rb+r), class=col
  }

  // intra-block combine of the two exemplar halves via LDS (reuse smem, 32KB):
  // red[half][brow_local 256][16], half = WE>>7.
  __syncthreads();
  float* red = (float*)smem;
  const int half = WE >> 7;
  #pragma unroll
  for (int fb = 0; fb < 4; ++fb)
    #pragma unroll
    for (int r = 0; r < 4; ++r)
      red[(((half << 8) | (WB + fb * 16 + rb + r)) << 4) | col] = csv[fb][r];
  __syncthreads();

  // sum halves, store block partial (256 x 16 f32) with aligned float4 stores.
  {
    const int o = tid * 8;        // 0..4095
    const int rl = o >> 4;        // brow_local 0..255
    const int c0 = o & 15;        // 0 or 8
    const float4* p0 = (const float4*)&red[(rl << 4) | c0];
    const float4* p1 = (const float4*)&red[((256 | rl) << 4) | c0];
    float4 a0 = p0[0], a1 = p0[1], b0 = p1[0], b1 = p1[1];
    float4 r0 = {a0.x + b0.x, a0.y + b0.y, a0.z + b0.z, a0.w + b0.w};
    float4 r1 = {a1.x + b1.x, a1.y + b1.y, a1.z + b1.z, a1.w + b1.w};
    float* g = &part[(((size_t)(bb * 256 + rl)) * NECH + be) * NCP + c0];
    *(float4*)g = r0;
    *(float4*)(g + 4) = r1;
  }
  __threadfence();
  grid.sync();

  // ================= phase C: reduce partials + gamma*log =====================
  if (wid < 4) {
    const float gamma = softplus(gu[0]) + EPSF;
    const int b = orig * 4 + wid;
    const int cl = lane & 15, ch0 = lane >> 4;
    const float* p = part + (size_t)b * NECH * NCP;
    float v = 0.f;
    #pragma unroll
    for (int k = 0; k < 16; ++k)
      v += p[(ch0 + 4 * k) * NCP + cl];
    v += __shfl_xor(v, 16, 64);
    v += __shfl_xor(v, 32, 64);
    if (lane < NC) out[b * NC + lane] = gamma * logf(v + EPSF);
  }
}

extern "C" void kernel_launch(void* const* d_in, const int* in_sizes, int n_in,
                              void* d_out, int out_size, void* d_ws, size_t ws_size,
                              hipStream_t stream) {
  const float* x  = (const float*)d_in[0];
  const float* ex = (const float*)d_in[1];
  const int* labels = (const int*)d_in[2];
  const float* wu = (const float*)d_in[3];
  const float* gu = (const float*)d_in[4];
  const float* bu = (const float*)d_in[5];
  float* out = (float*)d_out;
  const int B = in_sizes[0] / DDIM;   // 1024
  const int N = in_sizes[2];          // 16384

  char* ws = (char*)d_ws;
  const size_t off_x2w  = 0;
  const size_t off_e2w  = off_x2w + (size_t)B * 4;
  const size_t off_xbf  = off_e2w + (size_t)N * 4;
  const size_t off_ebf  = off_xbf + (size_t)B * DDIM * 2;
  const size_t off_part = off_ebf + (size_t)N * DDIM * 2;
  const size_t need     = off_part + (size_t)B * NECH * NCP * 4;
  if (ws_size < need) return;   // insufficient scratch; fail loudly (zeros)

  float* x2w  = (float*)(ws + off_x2w);
  float* e2w  = (float*)(ws + off_e2w);
  unsigned short* xbf = (unsigned short*)(ws + off_xbf);
  unsigned short* ebf = (unsigned short*)(ws + off_ebf);
  float* part = (float*)(ws + off_part);

  void* args[] = {
    (void*)&x, (void*)&ex, (void*)&labels, (void*)&wu, (void*)&gu, (void*)&bu,
    (void*)&xbf, (void*)&ebf, (void*)&x2w, (void*)&e2w, (void*)&part, (void*)&out
  };
  (void)hipLaunchCooperativeKernel((void*)fused_all, dim3(256), dim3(512),
                                   args, 0, stream);
}

// Round 8
// 41.193 us; speedup vs baseline: 4.9412x; 4.9412x over previous
//
#include <hip/hip_runtime.h>
#include <hip/hip_bf16.h>
#include <cstdint>

// ExemplarAttention: logits[b,c] = gamma * log( sum_{n: label[n]=c} exp(-beta * d[b,n]) + eps )
// d[b,n] = x2w[b] + e2w[n] - 2 * sum_k (x[b,k]*w[k]) * E[n,k]
//
// Round 8: revert coop (r7: grid.sync cost 160us). Multi-kernel, but gemm now runs
// 2 blocks/CU: tile 256Ex128B, BK=32, dbuf LDS 48KB, grid 512, 8 waves (4E x 2B),
// wave tile 64x64. Row-pair XOR swizzle (ch128 ^= rp&7) -> 2 lanes/bank (free) on
// ds_read_b128, applied both-sides (pre-swizzled global source + swizzled read).
// prep_w folded into prep_rows (per-block redundant softmax); gamma inside reduce.

typedef __attribute__((ext_vector_type(4))) float f32x4;
typedef __attribute__((ext_vector_type(8))) __bf16 bf16x8;
typedef __attribute__((ext_vector_type(4))) _Float16 half4;
typedef __attribute__((ext_vector_type(4))) unsigned int u32x4;

#define DDIM 512
#define NC 10
#define NCP 16
#define NECH 64    // exemplar chunks (16384/256)
#define EPSF 1e-9f

typedef const __attribute__((address_space(1))) void* gas_ptr;
typedef __attribute__((address_space(3))) void* las_ptr;

__device__ inline void async16(const void* g, void* l) {
  __builtin_amdgcn_global_load_lds((gas_ptr)g, (las_ptr)l, 16, 0, 0);
}

__device__ inline unsigned short f2bf(float f) {
  unsigned int u = __float_as_uint(f);
  u += 0x7FFFu + ((u >> 16) & 1u);   // round-to-nearest-even
  return (unsigned short)(u >> 16);
}

__device__ inline float wave_sum(float v) {
  #pragma unroll
  for (int o = 32; o > 0; o >>= 1) v += __shfl_xor(v, o, 64);
  return v;
}

__device__ inline float softplus(float x) {
  return (x > 20.0f) ? x : log1pf(__expf(x));
}

// ---- kernel 1: per-row bf16 cast + weighted square sum; softmax(w) per block ----
// 512 threads, 8 rows/block. Blocks [0, nxb) process x (mulw=1), rest process ex.
__global__ __launch_bounds__(512) void prep_rows(
    const float* __restrict__ x, const float* __restrict__ ex,
    const float* __restrict__ wu,
    unsigned short* __restrict__ xbf, unsigned short* __restrict__ ebf,
    float* __restrict__ x2w, float* __restrict__ e2w, int nxb) {
  __shared__ float wlds[512];
  __shared__ float sm[16];
  const int tid = threadIdx.x, lane = tid & 63, wid = tid >> 6;

  // softmax(w) + eps, redundantly per block (kills the serial prep_w kernel)
  {
    float v = wu[tid];
    float m = v;
    #pragma unroll
    for (int o = 32; o > 0; o >>= 1) m = fmaxf(m, __shfl_xor(m, o, 64));
    if (lane == 0) sm[wid] = m;
    __syncthreads();
    float mm = sm[0];
    #pragma unroll
    for (int i = 1; i < 8; ++i) mm = fmaxf(mm, sm[i]);
    float e = __expf(v - mm);
    float s = wave_sum(e);
    if (lane == 0) sm[8 + wid] = s;
    __syncthreads();
    float ss = 0.f;
    #pragma unroll
    for (int i = 0; i < 8; ++i) ss += sm[8 + i];
    wlds[tid] = e / ss + EPSF;
    __syncthreads();
  }

  const float4 wa = *(const float4*)&wlds[lane * 8];
  const float4 wb = *(const float4*)&wlds[lane * 8 + 4];

  const float* in; unsigned short* obf; float* osq; int mulw; size_t row;
  if (blockIdx.x < (unsigned)nxb) {
    in = x; obf = xbf; osq = x2w; mulw = 1;
    row = (size_t)blockIdx.x * 8 + wid;
  } else {
    in = ex; obf = ebf; osq = e2w; mulw = 0;
    row = (size_t)(blockIdx.x - nxb) * 8 + wid;
  }
  const float* p = in + row * DDIM + lane * 8;
  float4 va = *(const float4*)(p);
  float4 vb = *(const float4*)(p + 4);
  float s = va.x * va.x * wa.x + va.y * va.y * wa.y + va.z * va.z * wa.z + va.w * va.w * wa.w
          + vb.x * vb.x * wb.x + vb.y * vb.y * wb.y + vb.z * vb.z * wb.z + vb.w * vb.w * wb.w;
  u32x4 pk;
  if (mulw) {
    pk[0] = (unsigned)f2bf(va.x * wa.x) | ((unsigned)f2bf(va.y * wa.y) << 16);
    pk[1] = (unsigned)f2bf(va.z * wa.z) | ((unsigned)f2bf(va.w * wa.w) << 16);
    pk[2] = (unsigned)f2bf(vb.x * wb.x) | ((unsigned)f2bf(vb.y * wb.y) << 16);
    pk[3] = (unsigned)f2bf(vb.z * wb.z) | ((unsigned)f2bf(vb.w * wb.w) << 16);
  } else {
    pk[0] = (unsigned)f2bf(va.x) | ((unsigned)f2bf(va.y) << 16);
    pk[1] = (unsigned)f2bf(va.z) | ((unsigned)f2bf(va.w) << 16);
    pk[2] = (unsigned)f2bf(vb.x) | ((unsigned)f2bf(vb.y) << 16);
    pk[3] = (unsigned)f2bf(vb.z) | ((unsigned)f2bf(vb.w) << 16);
  }
  *(u32x4*)(obf + row * DDIM + lane * 8) = pk;
  s = wave_sum(s);
  if (lane == 0) osq[row] = s;
}

// ---- kernel 2: fused GEMM + exp + class partial reduce ----------------------
// grid: 512 blocks (64 e-tiles x 8 b-tiles), 512 threads = 8 waves (4E x 2B).
// Tile 256E x 128B, BK=32, dbuf LDS = 2 x (E 16KB + X 8KB) = 48KB -> 2 blocks/CU.
// Row-pair swizzle: LDS row-pair rp (128B) holds chunks c; global chunk c' = c ^ (rp&7),
// row = rp*2 + (c'>>2), 16B-chunk = c'&3. ds_read uses the same mapping.
// part layout: part[b_global][echunk][NCP], echunk in [0,64).
__global__ __launch_bounds__(512, 4) void gemm_fused(
    const unsigned short* __restrict__ Ebf, const unsigned short* __restrict__ Xbf,
    const int* __restrict__ labels, const float* __restrict__ x2w,
    const float* __restrict__ e2w, const float* __restrict__ bu,
    float* __restrict__ part) {
  // buffer: [E 8192 shorts | X 4096 shorts] x 2 = 24576 shorts = 48KB
  __shared__ __attribute__((aligned(16))) unsigned short smem[2 * 12288];
  __shared__ int lab[256];
  const int tid = threadIdx.x, lane = tid & 63, wid = tid >> 6;

  // XCD-aware bijective swizzle: 512 blocks; XCD x gets e-tiles [x*8,x*8+8) x 8 b-tiles.
  const int orig = blockIdx.x;             // 0..511
  const int xcd = orig & 7;
  const int local = orig >> 3;             // 0..63
  const int be = xcd * 8 + (local >> 3);   // exemplar tile 0..63
  const int bb = local & 7;                // batch tile 0..7

  if (tid < 256) lab[tid] = labels[be * 256 + tid];

  // --- staging sources (pre-swizzled) ---
  // E: 2 calls x 8KB; i = c*512+tid in [0,1024): lds_byte = i*16, rp = i>>3, cl = i&7.
  // X: 1 call x 8KB; i = tid in [0,512).
  const unsigned short* srcE[2];
  const unsigned short* srcX;
  int loffE[2], loffX;
  #pragma unroll
  for (int c = 0; c < 2; ++c) {
    int i = c * 512 + tid;
    int rp = i >> 3, cl = i & 7;
    int cp = cl ^ (rp & 7);
    int row = rp * 2 + (cp >> 2), kc = cp & 3;
    srcE[c] = Ebf + (size_t)(be * 256 + row) * DDIM + kc * 8;
    loffE[c] = i * 8;   // element offset (shorts)
  }
  {
    int rp = tid >> 3, cl = tid & 7;
    int cp = cl ^ (rp & 7);
    int row = rp * 2 + (cp >> 2), kc = cp & 3;
    srcX = Xbf + (size_t)(bb * 128 + row) * DDIM + kc * 8;
    loffX = 8192 + tid * 8;
  }

  const int WE = (wid >> 1) * 64;    // exemplar base (0,64,128,192)
  const int WB = (wid & 1) * 64;     // batch base (0,64)

  // --- fragment read byte-offsets, swizzle-matched ---
  // row r, chunk ch (= lane>>4): byte = (r>>1)*128 + ((((r&1)<<2)|ch) ^ ((r>>1)&7))*16
  int eoff[4], xoff[4];
  {
    const int ch = lane >> 4;
    #pragma unroll
    for (int f = 0; f < 4; ++f) {
      int er = WE + f * 16 + (lane & 15);
      eoff[f] = (er >> 1) * 128 + (((((er & 1) << 2) | ch) ^ ((er >> 1) & 7)) * 16);
      int xr = WB + f * 16 + (lane & 15);
      xoff[f] = 16384 + (xr >> 1) * 128 + (((((xr & 1) << 2) | ch) ^ ((xr >> 1) & 7)) * 16);
    }
  }

  // prologue: stage K-tile 0 into buffer 0
  async16(srcE[0], &smem[loffE[0]]);
  async16(srcE[1], &smem[loffE[1]]);
  async16(srcX, &smem[loffX]);
  srcE[0] += 32; srcE[1] += 32; srcX += 32;
  __syncthreads();   // drains vmcnt -> buffer 0 ready

  f32x4 acc[4][4] = {};
  int cur = 0;
  for (int kt = 0; kt < 16; ++kt) {
    if (kt < 15) {   // issue next tile into the other buffer; lands under compute
      const int nb = (cur ^ 1) * 12288;
      async16(srcE[0], &smem[nb + loffE[0]]);
      async16(srcE[1], &smem[nb + loffE[1]]);
      async16(srcX, &smem[nb + loffX]);
      srcE[0] += 32; srcE[1] += 32; srcX += 32;
    }
    const char* base = (const char*)&smem[cur * 12288];
    bf16x8 ef[4], xf[4];
    #pragma unroll
    for (int f = 0; f < 4; ++f) {
      ef[f] = *(const bf16x8*)(base + eoff[f]);
      xf[f] = *(const bf16x8*)(base + xoff[f]);
    }
    #pragma unroll
    for (int fe = 0; fe < 4; ++fe)
      #pragma unroll
      for (int fb = 0; fb < 4; ++fb)
        acc[fe][fb] = __builtin_amdgcn_mfma_f32_16x16x32_bf16(ef[fe], xf[fb], acc[fe][fb], 0, 0, 0);
    __syncthreads();   // all reads of cur done + next-tile loads landed
    cur ^= 1;
  }

  // epilogue: sim = exp(-beta*(x2w + e2w - 2*cross)); class-reduce via one-hot MFMA.
  const float beta = softplus(bu[0]) + EPSF;
  const int rb = (lane >> 4) * 4;   // row base within 16x16 fragment
  const int col = lane & 15;        // batch col in acc frags; class in cs frags
  float e2v[4][4];
  #pragma unroll
  for (int fe = 0; fe < 4; ++fe)
    #pragma unroll
    for (int r = 0; r < 4; ++r)
      e2v[fe][r] = e2w[be * 256 + WE + fe * 16 + rb + r];
  half4 oh[4];
  #pragma unroll
  for (int fe = 0; fe < 4; ++fe)
    #pragma unroll
    for (int i = 0; i < 4; ++i)
      oh[fe][i] = (lab[WE + fe * 16 + rb + i] == col) ? (_Float16)1.0f : (_Float16)0.0f;

  f32x4 csv[4];
  #pragma unroll
  for (int fb = 0; fb < 4; ++fb) {
    const float xv = x2w[bb * 128 + WB + fb * 16 + col];
    f32x4 cs = {0.f, 0.f, 0.f, 0.f};
    #pragma unroll
    for (int fe = 0; fe < 4; ++fe) {
      half4 sa;
      #pragma unroll
      for (int r = 0; r < 4; ++r)
        sa[r] = (_Float16)__expf(-beta * (xv + e2v[fe][r] - 2.0f * acc[fe][fb][r]));
      cs = __builtin_amdgcn_mfma_f32_16x16x16f16(sa, oh[fe], cs, 0, 0, 0);
    }
    csv[fb] = cs;   // cs[r]: class-sum for batch row (WB+fb*16+rb+r), class=col
  }

  // intra-block combine of the 4 exemplar quarters via LDS (reuse smem, 32KB):
  // red[quad][brow_local 128][16], quad = WE>>6.
  __syncthreads();
  float* red = (float*)smem;
  const int quad = WE >> 6;
  #pragma unroll
  for (int fb = 0; fb < 4; ++fb)
    #pragma unroll
    for (int r = 0; r < 4; ++r)
      red[(((quad << 7) | (WB + fb * 16 + rb + r)) << 4) | col] = csv[fb][r];
  __syncthreads();

  // sum quarters, store block partial (128 x 16 f32) with aligned float4 stores.
  {
    const int o = tid * 4;        // 0..2047
    const int rl = o >> 4;        // brow_local 0..127
    const int c0 = o & 12;        // 0,4,8,12
    float4 v0 = *(const float4*)&red[(rl << 4) | c0];
    float4 v1 = *(const float4*)&red[((128 | rl) << 4) | c0];
    float4 v2 = *(const float4*)&red[((256 | rl) << 4) | c0];
    float4 v3 = *(const float4*)&red[((384 | rl) << 4) | c0];
    float4 r0 = {v0.x + v1.x + v2.x + v3.x, v0.y + v1.y + v2.y + v3.y,
                 v0.z + v1.z + v2.z + v3.z, v0.w + v1.w + v2.w + v3.w};
    *(float4*)&part[(((size_t)(bb * 128 + rl)) * NECH + be) * NCP + c0] = r0;
  }
}

// ---- kernel 3: logits = gamma * log( sum_ne part[b][ne][c] + eps ) ----------
__global__ __launch_bounds__(256) void reduce_logits(
    const float* __restrict__ part, const float* __restrict__ gu,
    float* __restrict__ out) {
  const int lane = threadIdx.x & 63, wd = threadIdx.x >> 6;
  const int b = blockIdx.x * 4 + wd;
  const int cl = lane & 15, ch0 = lane >> 4;
  const float* p = part + (size_t)b * NECH * NCP;
  float v = 0.f;
  #pragma unroll
  for (int k = 0; k < 16; ++k)
    v += p[(ch0 + 4 * k) * NCP + cl];
  v += __shfl_xor(v, 16, 64);
  v += __shfl_xor(v, 32, 64);
  if (lane < NC) {
    const float gamma = softplus(gu[0]) + EPSF;
    out[b * NC + lane] = gamma * logf(v + EPSF);
  }
}

extern "C" void kernel_launch(void* const* d_in, const int* in_sizes, int n_in,
                              void* d_out, int out_size, void* d_ws, size_t ws_size,
                              hipStream_t stream) {
  const float* x  = (const float*)d_in[0];
  const float* ex = (const float*)d_in[1];
  const int* labels = (const int*)d_in[2];
  const float* wu = (const float*)d_in[3];
  const float* gu = (const float*)d_in[4];
  const float* bu = (const float*)d_in[5];
  float* out = (float*)d_out;
  const int B = in_sizes[0] / DDIM;   // 1024
  const int N = in_sizes[2];          // 16384

  char* ws = (char*)d_ws;
  const size_t off_x2w  = 0;
  const size_t off_e2w  = off_x2w + (size_t)B * 4;
  const size_t off_xbf  = off_e2w + (size_t)N * 4;
  const size_t off_ebf  = off_xbf + (size_t)B * DDIM * 2;
  const size_t off_part = off_ebf + (size_t)N * DDIM * 2;
  const size_t need     = off_part + (size_t)B * NECH * NCP * 4;
  if (ws_size < need) return;   // insufficient scratch; fail loudly (zeros)

  float* x2w  = (float*)(ws + off_x2w);
  float* e2w  = (float*)(ws + off_e2w);
  unsigned short* xbf = (unsigned short*)(ws + off_xbf);
  unsigned short* ebf = (unsigned short*)(ws + off_ebf);
  float* part = (float*)(ws + off_part);

  prep_rows<<<(B + N) / 8, 512, 0, stream>>>(x, ex, wu, xbf, ebf, x2w, e2w, B / 8);
  gemm_fused<<<(N / 256) * (B / 128), 512, 0, stream>>>(ebf, xbf, labels, x2w, e2w, bu, part);
  reduce_logits<<<B / 4, 256, 0, stream>>>(part, gu, out);
}

// Round 9
// 39.941 us; speedup vs baseline: 5.0960x; 1.0313x over previous
//
#include <hip/hip_runtime.h>
#include <hip/hip_bf16.h>
#include <cstdint>

// ExemplarAttention: logits[b,c] = gamma * log( sum_{n: label[n]=c} exp(-beta * d[b,n]) + eps )
// d[b,n] = x2w[b] + e2w[n] - 2 * sum_k (x[b,k]*w[k]) * E[n,k]
//
// Round 9: FULLY FUSED gemm. Each block: in-block softmax(w); reg-stages its own E/X
// f32 tiles (converting to bf16 via v_cvt_pk_bf16_f32 and accumulating e2w/x2w during
// conversion); 256x256 tile, BK=32, dbuf 64KB LDS; linear ds_write (conflict-free) with
// pre-swizzled global source so the r5-proven swizzled fragment reads still work;
// one-hot-MFMA class reduce epilogue (validated r2..r8). Eliminates the prep kernel
// (51MB of traffic + a launch gap) and all bf16/e2w/x2w global round-trips.
// Only 2 kernels: gemm_mega + reduce_logits.

typedef __attribute__((ext_vector_type(4))) float f32x4;
typedef __attribute__((ext_vector_type(8))) __bf16 bf16x8;
typedef __attribute__((ext_vector_type(4))) _Float16 half4;
typedef __attribute__((ext_vector_type(4))) unsigned int u32x4;

#define DDIM 512
#define NC 10
#define NCP 16
#define NECH 64    // exemplar chunks (16384/256)
#define EPSF 1e-9f

__device__ inline float wave_sum(float v) {
  #pragma unroll
  for (int o = 32; o > 0; o >>= 1) v += __shfl_xor(v, o, 64);
  return v;
}

__device__ inline float softplus(float x) {
  return (x > 20.0f) ? x : log1pf(__expf(x));
}

// pack 2 f32 -> 2 bf16 (RNE), lo -> bits[15:0]
__device__ inline unsigned cvtpk(float lo, float hi) {
  unsigned r;
  asm("v_cvt_pk_bf16_f32 %0, %1, %2" : "=v"(r) : "v"(lo), "v"(hi));
  return r;
}

// ---- kernel 1: fused everything-but-final-reduce ----------------------------
// grid: 256 blocks (64 e-tiles x 4 b-tiles), 512 threads = 8 waves (2E x 4B),
// wave tile 128x64. Tile 256E x 256B, BK=32, dbuf LDS 2 x (E 16KB | X 16KB) = 64KB.
// LDS chunk q (16B) holds global (row = q>>2, kchunk = (q&3)^(row&3)); staging thread
// t writes LDS-linear (q = c*512+t) from the pre-swizzled global chunk; fragment
// readers use byte = row*64 + ((ch^(row&3))*16)  [both-sides swizzle, rule #21].
__global__ __launch_bounds__(512, 2) void gemm_mega(
    const float* __restrict__ x, const float* __restrict__ ex,
    const int* __restrict__ labels, const float* __restrict__ wu,
    const float* __restrict__ bu, float* __restrict__ part) {
  __shared__ __attribute__((aligned(16))) unsigned short smem[2 * 16384];  // 64KB dbuf
  __shared__ float wlds[512];
  __shared__ float sm[16];
  __shared__ float e2l[256];
  __shared__ float x2l[256];
  __shared__ int lab[256];
  const int tid = threadIdx.x, lane = tid & 63, wid = tid >> 6;

  // XCD-aware bijective swizzle: XCD x owns e-tiles [x*8, x*8+8) x 4 b-tiles.
  const int orig = blockIdx.x;             // 0..255
  const int xcd = orig & 7;
  const int local = orig >> 3;             // 0..31
  const int be = xcd * 8 + (local >> 2);   // exemplar tile 0..63
  const int bb = local & 3;                // batch tile 0..3

  if (tid < 256) lab[tid] = labels[be * 256 + tid];

  // ---- in-block softmax(w) + eps -> wlds ----
  {
    float v = wu[tid];
    float m = v;
    #pragma unroll
    for (int o = 32; o > 0; o >>= 1) m = fmaxf(m, __shfl_xor(m, o, 64));
    if (lane == 0) sm[wid] = m;
    __syncthreads();
    float mm = sm[0];
    #pragma unroll
    for (int i = 1; i < 8; ++i) mm = fmaxf(mm, sm[i]);
    float e = __expf(v - mm);
    float s = wave_sum(e);
    if (lane == 0) sm[8 + wid] = s;
    __syncthreads();
    float ss = 0.f;
    #pragma unroll
    for (int i = 0; i < 8; ++i) ss += sm[8 + i];
    wlds[tid] = e / ss + EPSF;
    __syncthreads();
  }

  // ---- staging geometry (reg-staged, pre-swizzled source) ----
  const int srow = tid >> 2;                    // 0..127 (row base; +128 for c=1)
  const int kc = (tid & 3) ^ (srow & 3);        // fixed k-chunk 0..3 (8 f32 each)
  const float* eP0 = ex + (size_t)(be * 256 + srow) * DDIM + kc * 8;
  const float* eP1 = eP0 + (size_t)128 * DDIM;
  const float* xP0 = x + (size_t)(bb * 256 + srow) * DDIM + kc * 8;
  const float* xP1 = xP0 + (size_t)128 * DDIM;
  const int dE0 = tid * 8,           dE1 = (512 + tid) * 8;        // shorts
  const int dX0 = 8192 + tid * 8,    dX1 = 8192 + (512 + tid) * 8;

  float e2a0 = 0.f, e2a1 = 0.f, x2a0 = 0.f, x2a1 = 0.f;

  // ---- fragment read byte-offsets (BK=32, swizzle-matched) ----
  const int WE = (wid >> 2) * 128;   // exemplar base (0 or 128)
  const int WB = (wid & 3) * 64;     // batch base (0,64,128,192)
  int eoff[8], xoff[4];
  {
    const int ch = lane >> 4;        // 0..3
    #pragma unroll
    for (int f = 0; f < 8; ++f) {
      int er = WE + f * 16 + (lane & 15);
      eoff[f] = er * 64 + ((ch ^ (er & 3)) * 16);
    }
    #pragma unroll
    for (int f = 0; f < 4; ++f) {
      int xr = WB + f * 16 + (lane & 15);
      xoff[f] = 16384 + xr * 64 + ((ch ^ (xr & 3)) * 16);
    }
  }

  float4 sE0a, sE0b, sE1a, sE1b, sX0a, sX0b, sX1a, sX1b;

#define ISSUE(KT) do {                                                  \
    const float* p0 = eP0 + (KT) * 32;                                  \
    const float* p1 = eP1 + (KT) * 32;                                  \
    const float* p2 = xP0 + (KT) * 32;                                  \
    const float* p3 = xP1 + (KT) * 32;                                  \
    sE0a = *(const float4*)p0; sE0b = *(const float4*)(p0 + 4);         \
    sE1a = *(const float4*)p1; sE1b = *(const float4*)(p1 + 4);         \
    sX0a = *(const float4*)p2; sX0b = *(const float4*)(p2 + 4);         \
    sX1a = *(const float4*)p3; sX1b = *(const float4*)(p3 + 4);         \
  } while (0)

#define CVTSTORE(KT, BUFS) do {                                         \
    const float4 w0 = *(const float4*)&wlds[(KT) * 32 + kc * 8];        \
    const float4 w1 = *(const float4*)&wlds[(KT) * 32 + kc * 8 + 4];    \
    u32x4 pk;                                                           \
    pk[0] = cvtpk(sE0a.x, sE0a.y); pk[1] = cvtpk(sE0a.z, sE0a.w);       \
    pk[2] = cvtpk(sE0b.x, sE0b.y); pk[3] = cvtpk(sE0b.z, sE0b.w);       \
    e2a0 += sE0a.x*sE0a.x*w0.x + sE0a.y*sE0a.y*w0.y                     \
          + sE0a.z*sE0a.z*w0.z + sE0a.w*sE0a.w*w0.w                     \
          + sE0b.x*sE0b.x*w1.x + sE0b.y*sE0b.y*w1.y                     \
          + sE0b.z*sE0b.z*w1.z + sE0b.w*sE0b.w*w1.w;                    \
    *(u32x4*)&smem[(BUFS) + dE0] = pk;                                  \
    pk[0] = cvtpk(sE1a.x, sE1a.y); pk[1] = cvtpk(sE1a.z, sE1a.w);       \
    pk[2] = cvtpk(sE1b.x, sE1b.y); pk[3] = cvtpk(sE1b.z, sE1b.w);       \
    e2a1 += sE1a.x*sE1a.x*w0.x + sE1a.y*sE1a.y*w0.y                     \
          + sE1a.z*sE1a.z*w0.z + sE1a.w*sE1a.w*w0.w                     \
          + sE1b.x*sE1b.x*w1.x + sE1b.y*sE1b.y*w1.y                     \
          + sE1b.z*sE1b.z*w1.z + sE1b.w*sE1b.w*w1.w;                    \
    *(u32x4*)&smem[(BUFS) + dE1] = pk;                                  \
    float a0 = sX0a.x*w0.x, a1 = sX0a.y*w0.y, a2 = sX0a.z*w0.z,         \
          a3 = sX0a.w*w0.w, a4 = sX0b.x*w1.x, a5 = sX0b.y*w1.y,         \
          a6 = sX0b.z*w1.z, a7 = sX0b.w*w1.w;                           \
    pk[0] = cvtpk(a0, a1); pk[1] = cvtpk(a2, a3);                       \
    pk[2] = cvtpk(a4, a5); pk[3] = cvtpk(a6, a7);                       \
    x2a0 += a0*sX0a.x + a1*sX0a.y + a2*sX0a.z + a3*sX0a.w               \
          + a4*sX0b.x + a5*sX0b.y + a6*sX0b.z + a7*sX0b.w;              \
    *(u32x4*)&smem[(BUFS) + dX0] = pk;                                  \
    a0 = sX1a.x*w0.x; a1 = sX1a.y*w0.y; a2 = sX1a.z*w0.z;               \
    a3 = sX1a.w*w0.w; a4 = sX1b.x*w1.x; a5 = sX1b.y*w1.y;               \
    a6 = sX1b.z*w1.z; a7 = sX1b.w*w1.w;                                 \
    pk[0] = cvtpk(a0, a1); pk[1] = cvtpk(a2, a3);                       \
    pk[2] = cvtpk(a4, a5); pk[3] = cvtpk(a6, a7);                       \
    x2a1 += a0*sX1a.x + a1*sX1a.y + a2*sX1a.z + a3*sX1a.w               \
          + a4*sX1b.x + a5*sX1b.y + a6*sX1b.z + a7*sX1b.w;              \
    *(u32x4*)&smem[(BUFS) + dX1] = pk;                                  \
  } while (0)

  // prologue: stage K-tile 0 into buffer 0
  ISSUE(0);
  CVTSTORE(0, 0);
  __syncthreads();

  f32x4 acc[8][4] = {};
  for (int kt = 0; kt < 16; ++kt) {
    const int cur = kt & 1;
    if (kt < 15) ISSUE(kt + 1);          // loads fly under the MFMA phase
    const char* base = (const char*)smem + cur * 32768;
    bf16x8 ef[8], xf[4];
    #pragma unroll
    for (int f = 0; f < 8; ++f) ef[f] = *(const bf16x8*)(base + eoff[f]);
    #pragma unroll
    for (int f = 0; f < 4; ++f) xf[f] = *(const bf16x8*)(base + xoff[f]);
    #pragma unroll
    for (int fe = 0; fe < 8; ++fe)
      #pragma unroll
      for (int fb = 0; fb < 4; ++fb)
        acc[fe][fb] = __builtin_amdgcn_mfma_f32_16x16x32_bf16(ef[fe], xf[fb], acc[fe][fb], 0, 0, 0);
    if (kt < 15) CVTSTORE(kt + 1, (cur ^ 1) * 16384);  // write other buffer
    __syncthreads();
  }
#undef ISSUE
#undef CVTSTORE

  // ---- finalize e2w / x2w: sum the 4 kc-threads of each row ----
  e2a0 += __shfl_xor(e2a0, 1, 64); e2a0 += __shfl_xor(e2a0, 2, 64);
  e2a1 += __shfl_xor(e2a1, 1, 64); e2a1 += __shfl_xor(e2a1, 2, 64);
  x2a0 += __shfl_xor(x2a0, 1, 64); x2a0 += __shfl_xor(x2a0, 2, 64);
  x2a1 += __shfl_xor(x2a1, 1, 64); x2a1 += __shfl_xor(x2a1, 2, 64);
  if ((tid & 3) == 0) {
    e2l[srow] = e2a0; e2l[srow + 128] = e2a1;
    x2l[srow] = x2a0; x2l[srow + 128] = x2a1;
  }
  __syncthreads();

  // ---- epilogue: sim = exp(-beta*d); class-reduce via one-hot MFMA ----
  const float beta = softplus(bu[0]) + EPSF;
  const int rb = (lane >> 4) * 4;
  const int col = lane & 15;
  float e2v[8][4];
  #pragma unroll
  for (int fe = 0; fe < 8; ++fe)
    #pragma unroll
    for (int r = 0; r < 4; ++r)
      e2v[fe][r] = e2l[WE + fe * 16 + rb + r];
  half4 oh[8];
  #pragma unroll
  for (int fe = 0; fe < 8; ++fe)
    #pragma unroll
    for (int i = 0; i < 4; ++i)
      oh[fe][i] = (lab[WE + fe * 16 + rb + i] == col) ? (_Float16)1.0f : (_Float16)0.0f;

  f32x4 csv[4];
  #pragma unroll
  for (int fb = 0; fb < 4; ++fb) {
    const float xv = x2l[WB + fb * 16 + col];
    f32x4 cs = {0.f, 0.f, 0.f, 0.f};
    #pragma unroll
    for (int fe = 0; fe < 8; ++fe) {
      half4 sa;
      #pragma unroll
      for (int r = 0; r < 4; ++r)
        sa[r] = (_Float16)__expf(-beta * (xv + e2v[fe][r] - 2.0f * acc[fe][fb][r]));
      cs = __builtin_amdgcn_mfma_f32_16x16x16f16(sa, oh[fe], cs, 0, 0, 0);
    }
    csv[fb] = cs;
  }

  // intra-block combine of the 2 exemplar halves via LDS (reuse smem, 32KB)
  float* red = (float*)smem;
  const int half = WE >> 7;
  #pragma unroll
  for (int fb = 0; fb < 4; ++fb)
    #pragma unroll
    for (int r = 0; r < 4; ++r)
      red[(((half << 8) | (WB + fb * 16 + rb + r)) << 4) | col] = csv[fb][r];
  __syncthreads();

  // sum halves, store block partial (256 x 16 f32) coalesced
  {
    const int o = tid * 8;        // 0..4095
    const int rl = o >> 4;        // brow_local 0..255
    const int c0 = o & 15;        // 0 or 8
    const float4* p0 = (const float4*)&red[(rl << 4) | c0];
    const float4* p1 = (const float4*)&red[((256 | rl) << 4) | c0];
    float4 a0 = p0[0], a1 = p0[1], b0 = p1[0], b1 = p1[1];
    float4 r0 = {a0.x + b0.x, a0.y + b0.y, a0.z + b0.z, a0.w + b0.w};
    float4 r1 = {a1.x + b1.x, a1.y + b1.y, a1.z + b1.z, a1.w + b1.w};
    float* g = &part[(((size_t)(bb * 256 + rl)) * NECH + be) * NCP + c0];
    *(float4*)g = r0;
    *(float4*)(g + 4) = r1;
  }
}

// ---- kernel 2: logits = gamma * log( sum_ne part[b][ne][c] + eps ) ----------
__global__ __launch_bounds__(256) void reduce_logits(
    const float* __restrict__ part, const float* __restrict__ gu,
    float* __restrict__ out) {
  const int lane = threadIdx.x & 63, wd = threadIdx.x >> 6;
  const int b = blockIdx.x * 4 + wd;
  const int cl = lane & 15, ch0 = lane >> 4;
  const float* p = part + (size_t)b * NECH * NCP;
  float v = 0.f;
  #pragma unroll
  for (int k = 0; k < 16; ++k)
    v += p[(ch0 + 4 * k) * NCP + cl];
  v += __shfl_xor(v, 16, 64);
  v += __shfl_xor(v, 32, 64);
  if (lane < NC) {
    const float gamma = softplus(gu[0]) + EPSF;
    out[b * NC + lane] = gamma * logf(v + EPSF);
  }
}

extern "C" void kernel_launch(void* const* d_in, const int* in_sizes, int n_in,
                              void* d_out, int out_size, void* d_ws, size_t ws_size,
                              hipStream_t stream) {
  const float* x  = (const float*)d_in[0];
  const float* ex = (const float*)d_in[1];
  const int* labels = (const int*)d_in[2];
  const float* wu = (const float*)d_in[3];
  const float* gu = (const float*)d_in[4];
  const float* bu = (const float*)d_in[5];
  float* out = (float*)d_out;
  const int B = in_sizes[0] / DDIM;   // 1024
  const int N = in_sizes[2];          // 16384

  float* part = (float*)d_ws;
  const size_t need = (size_t)B * NECH * NCP * 4;
  if (ws_size < need) return;   // insufficient scratch; fail loudly (zeros)

  gemm_mega<<<(N / 256) * (B / 256), 512, 0, stream>>>(x, ex, labels, wu, bu, part);
  reduce_logits<<<B / 4, 256, 0, stream>>>(part, gu, out);
}

// Round 10
// 37.787 us; speedup vs baseline: 5.3865x; 1.0570x over previous
//
#include <hip/hip_runtime.h>
#include <hip/hip_bf16.h>
#include <cstdint>

// ExemplarAttention: logits[b,c] = gamma * log( sum_{n: label[n]=c} exp(-beta * d[b,n]) + eps )
// d[b,n] = x2w[b] + e2w[n] - 2 * sum_k (x[b,k]*w[k]) * E[n,k]
//
// Round 10: r9's fused design, two fixes from its PMC postmortem:
//  (1) swizzle bit fix: BK=32 rows are 4 chunks; XOR on (er>>1)&3 (not er&3) spreads
//      16 lanes over 8 distinct 16B slots -> 2-way (free). r9's er&3 was 4-way (1.67M
//      conflicts). Source kc pre-swizzled to match; LDS writes stay linear.
//  (2) occupancy: 1024 threads / 16 waves (4E x 4B, wave tile 64x64, acc=64 regs)
//      -> 4 waves/SIMD instead of 2; __launch_bounds__(1024,4).
// Everything else (in-block softmax(w), reg-staged f32->bf16 cvt with fused e2w/x2w
// accumulation, dbuf LDS, one-hot-MFMA class reduce, no atomics) as r9.

typedef __attribute__((ext_vector_type(4))) float f32x4;
typedef __attribute__((ext_vector_type(8))) __bf16 bf16x8;
typedef __attribute__((ext_vector_type(4))) _Float16 half4;
typedef __attribute__((ext_vector_type(4))) unsigned int u32x4;

#define DDIM 512
#define NC 10
#define NCP 16
#define NECH 64    // exemplar chunks (16384/256)
#define EPSF 1e-9f

__device__ inline float softplus(float x) {
  return (x > 20.0f) ? x : log1pf(__expf(x));
}

// pack 2 f32 -> 2 bf16 (RNE), lo -> bits[15:0]
__device__ inline unsigned cvtpk(float lo, float hi) {
  unsigned r;
  asm("v_cvt_pk_bf16_f32 %0, %1, %2" : "=v"(r) : "v"(lo), "v"(hi));
  return r;
}

// ---- kernel 1: fused everything-but-final-reduce ----------------------------
// grid: 256 blocks (64 e-tiles x 4 b-tiles), 1024 threads = 16 waves (4E x 4B),
// wave tile 64x64. Tile 256E x 256B, BK=32, dbuf LDS 2 x (E 16KB | X 16KB) = 64KB.
// LDS chunk q (16B): row = q>>2, c = q&3, global kchunk = c ^ ((row>>1)&3).
// Staging thread t = q writes LDS-linear from the pre-swizzled global chunk; fragment
// readers use byte = row*64 + ((ch ^ ((row>>1)&3))*16)   [both-sides swizzle].
__global__ __launch_bounds__(1024, 4) void gemm_mega(
    const float* __restrict__ x, const float* __restrict__ ex,
    const int* __restrict__ labels, const float* __restrict__ wu,
    const float* __restrict__ bu, float* __restrict__ part) {
  __shared__ __attribute__((aligned(16))) unsigned short smem[2 * 16384];  // 64KB dbuf
  __shared__ float wlds[512];
  __shared__ float sm[16];
  __shared__ float e2l[256];
  __shared__ float x2l[256];
  __shared__ int lab[256];
  const int tid = threadIdx.x, lane = tid & 63, wid = tid >> 6;

  // XCD-aware bijective swizzle: XCD x owns e-tiles [x*8, x*8+8) x 4 b-tiles.
  const int orig = blockIdx.x;             // 0..255
  const int xcd = orig & 7;
  const int local = orig >> 3;             // 0..31
  const int be = xcd * 8 + (local >> 2);   // exemplar tile 0..63
  const int bb = local & 3;                // batch tile 0..3

  if (tid < 256) lab[tid] = labels[be * 256 + tid];

  // ---- in-block softmax(w) + eps -> wlds (threads 0..511) ----
  if (tid < 512) {
    float v = wu[tid];
    float m = v;
    #pragma unroll
    for (int o = 32; o > 0; o >>= 1) m = fmaxf(m, __shfl_xor(m, o, 64));
    if (lane == 0) sm[wid] = m;
    __syncthreads();
    float mm = sm[0];
    #pragma unroll
    for (int i = 1; i < 8; ++i) mm = fmaxf(mm, sm[i]);
    float e = __expf(v - mm);
    float s = e;
    #pragma unroll
    for (int o = 32; o > 0; o >>= 1) s += __shfl_xor(s, o, 64);
    if (lane == 0) sm[8 + wid] = s;
    __syncthreads();
    float ss = 0.f;
    #pragma unroll
    for (int i = 0; i < 8; ++i) ss += sm[8 + i];
    wlds[tid] = e / ss + EPSF;
  } else {
    __syncthreads();
    __syncthreads();
  }
  __syncthreads();

  // ---- staging geometry (reg-staged, pre-swizzled source) ----
  const int srow = tid >> 2;                       // 0..255
  const int kc = (tid & 3) ^ ((srow >> 1) & 3);    // fixed k-chunk 0..3 (8 f32 each)
  const float* eP = ex + (size_t)(be * 256 + srow) * DDIM + kc * 8;
  const float* xP = x + (size_t)(bb * 256 + srow) * DDIM + kc * 8;
  const int dE = tid * 8;            // shorts
  const int dX = 8192 + tid * 8;

  float e2a = 0.f, x2a = 0.f;

  // ---- fragment read byte-offsets (BK=32, swizzle-matched) ----
  const int WE = (wid >> 2) * 64;    // exemplar base (0,64,128,192)
  const int WB = (wid & 3) * 64;     // batch base (0,64,128,192)
  int eoff[4], xoff[4];
  {
    const int ch = lane >> 4;        // 0..3
    #pragma unroll
    for (int f = 0; f < 4; ++f) {
      int er = WE + f * 16 + (lane & 15);
      eoff[f] = er * 64 + ((ch ^ ((er >> 1) & 3)) * 16);
      int xr = WB + f * 16 + (lane & 15);
      xoff[f] = 16384 + xr * 64 + ((ch ^ ((xr >> 1) & 3)) * 16);
    }
  }

  float4 sEa, sEb, sXa, sXb;

#define ISSUE(KT) do {                                                  \
    const float* p0 = eP + (KT) * 32;                                   \
    const float* p1 = xP + (KT) * 32;                                   \
    sEa = *(const float4*)p0; sEb = *(const float4*)(p0 + 4);           \
    sXa = *(const float4*)p1; sXb = *(const float4*)(p1 + 4);           \
  } while (0)

#define CVTSTORE(KT, BUFS) do {                                         \
    const float4 w0 = *(const float4*)&wlds[(KT) * 32 + kc * 8];        \
    const float4 w1 = *(const float4*)&wlds[(KT) * 32 + kc * 8 + 4];    \
    u32x4 pk;                                                           \
    pk[0] = cvtpk(sEa.x, sEa.y); pk[1] = cvtpk(sEa.z, sEa.w);           \
    pk[2] = cvtpk(sEb.x, sEb.y); pk[3] = cvtpk(sEb.z, sEb.w);           \
    e2a += sEa.x*sEa.x*w0.x + sEa.y*sEa.y*w0.y                          \
         + sEa.z*sEa.z*w0.z + sEa.w*sEa.w*w0.w                          \
         + sEb.x*sEb.x*w1.x + sEb.y*sEb.y*w1.y                          \
         + sEb.z*sEb.z*w1.z + sEb.w*sEb.w*w1.w;                         \
    *(u32x4*)&smem[(BUFS) + dE] = pk;                                   \
    float a0 = sXa.x*w0.x, a1 = sXa.y*w0.y, a2 = sXa.z*w0.z,            \
          a3 = sXa.w*w0.w, a4 = sXb.x*w1.x, a5 = sXb.y*w1.y,            \
          a6 = sXb.z*w1.z, a7 = sXb.w*w1.w;                             \
    pk[0] = cvtpk(a0, a1); pk[1] = cvtpk(a2, a3);                       \
    pk[2] = cvtpk(a4, a5); pk[3] = cvtpk(a6, a7);                       \
    x2a += a0*sXa.x + a1*sXa.y + a2*sXa.z + a3*sXa.w                    \
         + a4*sXb.x + a5*sXb.y + a6*sXb.z + a7*sXb.w;                   \
    *(u32x4*)&smem[(BUFS) + dX] = pk;                                   \
  } while (0)

  // prologue: stage K-tile 0 into buffer 0
  ISSUE(0);
  CVTSTORE(0, 0);
  __syncthreads();

  f32x4 acc[4][4] = {};
  for (int kt = 0; kt < 16; ++kt) {
    const int cur = kt & 1;
    if (kt < 15) ISSUE(kt + 1);          // loads fly under the MFMA phase
    const char* base = (const char*)smem + cur * 32768;
    bf16x8 ef[4], xf[4];
    #pragma unroll
    for (int f = 0; f < 4; ++f) {
      ef[f] = *(const bf16x8*)(base + eoff[f]);
      xf[f] = *(const bf16x8*)(base + xoff[f]);
    }
    #pragma unroll
    for (int fe = 0; fe < 4; ++fe)
      #pragma unroll
      for (int fb = 0; fb < 4; ++fb)
        acc[fe][fb] = __builtin_amdgcn_mfma_f32_16x16x32_bf16(ef[fe], xf[fb], acc[fe][fb], 0, 0, 0);
    if (kt < 15) CVTSTORE(kt + 1, (cur ^ 1) * 16384);  // write other buffer
    __syncthreads();
  }
#undef ISSUE
#undef CVTSTORE

  // ---- finalize e2w / x2w: sum the 4 kc-threads of each row ----
  e2a += __shfl_xor(e2a, 1, 64); e2a += __shfl_xor(e2a, 2, 64);
  x2a += __shfl_xor(x2a, 1, 64); x2a += __shfl_xor(x2a, 2, 64);
  if ((tid & 3) == 0) {
    e2l[srow] = e2a;
    x2l[srow] = x2a;
  }
  __syncthreads();

  // ---- epilogue: sim = exp(-beta*d); class-reduce via one-hot MFMA ----
  const float beta = softplus(bu[0]) + EPSF;
  const int rb = (lane >> 4) * 4;
  const int col = lane & 15;
  float e2v[4][4];
  #pragma unroll
  for (int fe = 0; fe < 4; ++fe)
    #pragma unroll
    for (int r = 0; r < 4; ++r)
      e2v[fe][r] = e2l[WE + fe * 16 + rb + r];
  half4 oh[4];
  #pragma unroll
  for (int fe = 0; fe < 4; ++fe)
    #pragma unroll
    for (int i = 0; i < 4; ++i)
      oh[fe][i] = (lab[WE + fe * 16 + rb + i] == col) ? (_Float16)1.0f : (_Float16)0.0f;

  f32x4 csv[4];
  #pragma unroll
  for (int fb = 0; fb < 4; ++fb) {
    const float xv = x2l[WB + fb * 16 + col];
    f32x4 cs = {0.f, 0.f, 0.f, 0.f};
    #pragma unroll
    for (int fe = 0; fe < 4; ++fe) {
      half4 sa;
      #pragma unroll
      for (int r = 0; r < 4; ++r)
        sa[r] = (_Float16)__expf(-beta * (xv + e2v[fe][r] - 2.0f * acc[fe][fb][r]));
      cs = __builtin_amdgcn_mfma_f32_16x16x16f16(sa, oh[fe], cs, 0, 0, 0);
    }
    csv[fb] = cs;   // cs[r]: class-sum for batch row (WB+fb*16+rb+r), class=col
  }

  // intra-block combine of the 4 exemplar quarters via LDS (reuse smem, 64KB):
  // red[quad][brow_local 256][16], quad = WE>>6.
  float* red = (float*)smem;
  const int quad = WE >> 6;
  #pragma unroll
  for (int fb = 0; fb < 4; ++fb)
    #pragma unroll
    for (int r = 0; r < 4; ++r)
      red[((quad * 256 + (WB + fb * 16 + rb + r)) << 4) | col] = csv[fb][r];
  __syncthreads();

  // sum quarters, store block partial (256 x 16 f32) coalesced (float4/thread)
  {
    const int o = tid * 4;        // 0..4095
    const int rl = o >> 4;        // brow_local 0..255
    const int c0 = o & 12;        // 0,4,8,12
    float4 v0 = *(const float4*)&red[(rl << 4) | c0];
    float4 v1 = *(const float4*)&red[((256 + rl) << 4) | c0];
    float4 v2 = *(const float4*)&red[((512 + rl) << 4) | c0];
    float4 v3 = *(const float4*)&red[((768 + rl) << 4) | c0];
    float4 r0 = {v0.x + v1.x + v2.x + v3.x, v0.y + v1.y + v2.y + v3.y,
                 v0.z + v1.z + v2.z + v3.z, v0.w + v1.w + v2.w + v3.w};
    *(float4*)&part[(((size_t)(bb * 256 + rl)) * NECH + be) * NCP + c0] = r0;
  }
}

// ---- kernel 2: logits = gamma * log( sum_ne part[b][ne][c] + eps ) ----------
__global__ __launch_bounds__(256) void reduce_logits(
    const float* __restrict__ part, const float* __restrict__ gu,
    float* __restrict__ out) {
  const int lane = threadIdx.x & 63, wd = threadIdx.x >> 6;
  const int b = blockIdx.x * 4 + wd;
  const int cl = lane & 15, ch0 = lane >> 4;
  const float* p = part + (size_t)b * NECH * NCP;
  float v = 0.f;
  #pragma unroll
  for (int k = 0; k < 16; ++k)
    v += p[(ch0 + 4 * k) * NCP + cl];
  v += __shfl_xor(v, 16, 64);
  v += __shfl_xor(v, 32, 64);
  if (lane < NC) {
    const float gamma = softplus(gu[0]) + EPSF;
    out[b * NC + lane] = gamma * logf(v + EPSF);
  }
}

extern "C" void kernel_launch(void* const* d_in, const int* in_sizes, int n_in,
                              void* d_out, int out_size, void* d_ws, size_t ws_size,
                              hipStream_t stream) {
  const float* x  = (const float*)d_in[0];
  const float* ex = (const float*)d_in[1];
  const int* labels = (const int*)d_in[2];
  const float* wu = (const float*)d_in[3];
  const float* gu = (const float*)d_in[4];
  const float* bu = (const float*)d_in[5];
  float* out = (float*)d_out;
  const int B = in_sizes[0] / DDIM;   // 1024
  const int N = in_sizes[2];          // 16384

  float* part = (float*)d_ws;
  const size_t need = (size_t)B * NECH * NCP * 4;
  if (ws_size < need) return;   // insufficient scratch; fail loudly (zeros)

  gemm_mega<<<(N / 256) * (B / 256), 1024, 0, stream>>>(x, ex, labels, wu, bu, part);
  reduce_logits<<<B / 4, 256, 0, stream>>>(part, gu, out);
}